// Round 8
// baseline (209.533 us; speedup 1.0000x reference)
//
#include <hip/hip_runtime.h>
#include <hip/hip_bf16.h>
#include <cstdint>

// adknnLoss: N=8192, M=128.
//   A = L*X; B = (X@Wnet + bnet)*X
//   dist[i,j] = ||A_i - B_j||; drum = exp(-dist)
//   pred = (drum@Y)/drum.sum(1); loss = sum((Y-pred)^2)
//
// Round 8: r3's pairwise (swizzled fragment layout, rt=2, 512-col chunks,
// grid (64,16)) -- best measured config (~42us) -- with launch_bounds(256,6)
// for 6 waves/SIMD (VGPR cap 84 vs 76 used in r3). Prep replaced by r7's
// single-MFMA high-occupancy version emitting swizzled stores.
//   w = exp(-dist) = 2^(-sqrt(K2*d2)), K2=(log2 e)^2 folded into norms;
//   norms from bf16-rounded a/b so d2 >= ~0.
//
// Swizzled fragment layout (A and B operands of mfma_f32_16x16x32_bf16):
//   idx(row,k) = (row>>4)*2048 + (k>>5)*512 + ((k>>3)&3)*128 + (row&15)*8 + (k&7)
// Wave fragment load for (group g, ks): base + g*2048 + ks*512 + lane*8
// -> lane-contiguous 16 B/lane global_load_dwordx4 (8 cache lines/instr).

#define N_ 8192
#define K2_ 2.0813689810056077f      // (log2 e)^2
#define NEG2K2_ -4.1627379620112154f // -2*(log2 e)^2

typedef __bf16 bf16x8 __attribute__((ext_vector_type(8)));
typedef float  f32x4  __attribute__((ext_vector_type(4)));

// pack two fp32 -> bf16 RNE pair (low = f0, high = f1)
__device__ __forceinline__ uint32_t pk2(float f0, float f1) {
    uint32_t u0 = __float_as_uint(f0), u1 = __float_as_uint(f1);
    u0 = u0 + 0x7fffu + ((u0 >> 16) & 1u);
    u1 = u1 + 0x7fffu + ((u1 >> 16) & 1u);
    return (u0 >> 16) | (u1 & 0xffff0000u);
}
// same, also returning the rounded values (for norms)
__device__ __forceinline__ uint32_t rne2(float f0, float f1, float& r0, float& r1) {
    uint32_t u0 = __float_as_uint(f0), u1 = __float_as_uint(f1);
    uint32_t t0 = u0 + 0x7fffu + ((u0 >> 16) & 1u);
    uint32_t t1 = u1 + 0x7fffu + ((u1 >> 16) & 1u);
    r0 = __uint_as_float(t0 & 0xffff0000u);
    r1 = __uint_as_float(t1 & 0xffff0000u);
    return (t0 >> 16) | (t1 & 0xffff0000u);
}

// ---------------------------------------------------------------------------
// wprep: 32 blocks x 256 thr. Packs Wnet into A-operand fragment layout
// (Wbf[ct*1024 + ks*256 + lane*4 + jpair], dword = bf16 pair along k);
// zeroes naS/sumw/sumwy; seeds nbY = (0, Y).
// ---------------------------------------------------------------------------
__global__ __launch_bounds__(256) void wprep_kernel(
    const float* __restrict__ Wnet, const float* __restrict__ Y,
    uint32_t* __restrict__ Wbf, float* __restrict__ naS,
    float2* __restrict__ nbY, float* __restrict__ sumw,
    float* __restrict__ sumwy)
{
    const int t  = blockIdx.x * 256 + threadIdx.x;  // 0..8191
    const int f2 = t * 2;                           // bf16 element index
    const int j0   = f2 & 7;
    const int lane = (f2 >> 3) & 63;
    const int ks   = (f2 >> 9) & 3;
    const int ct   = f2 >> 11;
    const int k0   = ks * 32 + (lane >> 4) * 8 + j0;
    const int col  = ct * 16 + (lane & 15);
    Wbf[t] = pk2(Wnet[k0 * 128 + col], Wnet[(k0 + 1) * 128 + col]);
    naS[t] = 0.f;
    sumw[t] = 0.f;
    sumwy[t] = 0.f;
    nbY[t] = make_float2(0.f, Y[t]);
}

// ---------------------------------------------------------------------------
// prep: 1024 blocks x 256 thr (4 waves). block = (rowgrp=bx>>1, chalf=bx&1):
// 16 rows, col-tile ct = chalf*4 + wv (16 cols per wave).
// net-GEMM transposed: D[m=netcol][n=samplerow] = sum_c Wnet[c][col]*X[row][c]
//   A-operand: wfrag 16B loads from Wbf (fragment-ready)
//   B-operand: xfrag packed from X row (contiguous fp32 loads)
//   D: lane -> (col = ct*16 + quad*4 + reg, row = row0 + ln16)
// Epilogue: b=(D+bnet)*X, a=L*X, RNE->bf16, SWIZZLED 8B stores (pr0+pr1
// pairs contiguous since (col0&7) in {0,4}). Norms: quad-shuffle + LDS +
// atomicAdd into naS / nbY.x.
// ---------------------------------------------------------------------------
__global__ __launch_bounds__(256) void prep_kernel(
    const float* __restrict__ L, const float* __restrict__ X,
    const uint32_t* __restrict__ Wbf, const float* __restrict__ bnet,
    unsigned short* __restrict__ Abf, unsigned short* __restrict__ Bbf,
    float* __restrict__ naS, float2* __restrict__ nbY)
{
    __shared__ float ldsNa[4][16], ldsNb[4][16];
    const int tid  = threadIdx.x;
    const int wv   = tid >> 6;
    const int lane = tid & 63;
    const int ln16 = lane & 15;
    const int quad = lane >> 4;
    const int rowgrp = blockIdx.x >> 1;
    const int chalf  = blockIdx.x & 1;
    const int row0 = rowgrp * 16;
    const int row  = row0 + ln16;
    const int ct   = chalf * 4 + wv;

    // X row as B-operand fragments
    bf16x8 xfrag[4];
    #pragma unroll
    for (int ks = 0; ks < 4; ++ks) {
        const float* xp = X + (size_t)row * 128 + ks * 32 + quad * 8;
        const float4 f0 = *(const float4*)xp;
        const float4 f1 = *(const float4*)(xp + 4);
        uint4 u = make_uint4(pk2(f0.x, f0.y), pk2(f0.z, f0.w),
                             pk2(f1.x, f1.y), pk2(f1.z, f1.w));
        xfrag[ks] = *(bf16x8*)&u;
    }
    // Wnet^T fragments: direct loads (packed by wprep)
    bf16x8 wfrag[4];
    #pragma unroll
    for (int ks = 0; ks < 4; ++ks) {
        uint4 u = *(const uint4*)(Wbf + (size_t)ct * 1024 + ks * 256 + lane * 4);
        wfrag[ks] = *(bf16x8*)&u;
    }

    f32x4 s = {0.f, 0.f, 0.f, 0.f};
    #pragma unroll
    for (int ks = 0; ks < 4; ++ks)
        s = __builtin_amdgcn_mfma_f32_16x16x32_bf16(wfrag[ks], xfrag[ks], s, 0, 0, 0);

    float na_ = 0.f, nb_ = 0.f;
    uint32_t pa[2], pb[2];
    const int col0 = ct * 16 + quad * 4;   // cols col0 .. col0+3
    #pragma unroll
    for (int pr = 0; pr < 2; ++pr) {
        const int colb = col0 + pr * 2;
        const float2 x2  = *(const float2*)(X + (size_t)row * 128 + colb);
        const float2 l2  = *(const float2*)(L + (size_t)row * 128 + colb);
        const float2 bn2 = *(const float2*)(bnet + colb);
        float b0 = (s[pr * 2 + 0] + bn2.x) * x2.x;
        float b1 = (s[pr * 2 + 1] + bn2.y) * x2.y;
        float a0 = l2.x * x2.x;
        float a1 = l2.y * x2.y;
        float ra0, ra1, rb0, rb1;
        pa[pr] = rne2(a0, a1, ra0, ra1);
        pb[pr] = rne2(b0, b1, rb0, rb1);
        na_ = fmaf(ra0, ra0, na_); na_ = fmaf(ra1, ra1, na_);
        nb_ = fmaf(rb0, rb0, nb_); nb_ = fmaf(rb1, rb1, nb_);
    }
    // swizzled store: cols col0..col0+3 are contiguous shorts at idx(row,col0)
    {
        const size_t off = (size_t)rowgrp * 2048 + (size_t)(col0 >> 5) * 512
                         + (size_t)((col0 >> 3) & 3) * 128
                         + (size_t)ln16 * 8 + (col0 & 7);
        *(uint2*)(Abf + off) = make_uint2(pa[0], pa[1]);
        *(uint2*)(Bbf + off) = make_uint2(pb[0], pb[1]);
    }

    // reduce this wave's 16-col partials over quads, then atomic-accumulate
    na_ += __shfl_xor(na_, 16, 64);  na_ += __shfl_xor(na_, 32, 64);
    nb_ += __shfl_xor(nb_, 16, 64);  nb_ += __shfl_xor(nb_, 32, 64);
    if (quad == 0) { ldsNa[wv][ln16] = na_; ldsNb[wv][ln16] = nb_; }
    __syncthreads();
    if (tid < 16) {
        float v = ldsNa[0][tid] + ldsNa[1][tid] + ldsNa[2][tid] + ldsNa[3][tid];
        atomicAdd(&naS[row0 + tid], K2_ * v);
    } else if (tid < 32) {
        int r = tid - 16;
        float v = ldsNb[0][r] + ldsNb[1][r] + ldsNb[2][r] + ldsNb[3][r];
        atomicAdd(&nbY[row0 + r].x, K2_ * v);
    }
}

// ---------------------------------------------------------------------------
// pairwise (r3 structure): grid (64, 16), 256 thr (4 waves), i-tile 128 rows
// (32/wave, rt=2), j-chunk 512 cols = 32 groups of 16. No LDS, no barriers.
// Swizzled lane-contiguous B loads. launch_bounds(256,6): VGPR cap 84.
// ---------------------------------------------------------------------------
__global__ __launch_bounds__(256, 6) void pairwise_kernel(
    const unsigned short* __restrict__ Asw, const unsigned short* __restrict__ Bsw,
    const float* __restrict__ naS, const float2* __restrict__ nbY,
    float* __restrict__ sumw, float* __restrict__ sumwy)
{
    const int tid  = threadIdx.x;
    const int wv   = tid >> 6;
    const int lane = tid & 63;
    const int ln16 = lane & 15;
    const int quad = lane >> 4;
    const int i0   = blockIdx.x * 128;
    const int j0   = blockIdx.y * 512;

    // persistent A fragments + scaled norms
    bf16x8 afrag[2][4];
    float  na[2][4];
    #pragma unroll
    for (int rt = 0; rt < 2; ++rt) {
        const int gA = (i0 >> 4) + wv * 2 + rt;
        const unsigned short* ap = Asw + (size_t)gA * 2048 + lane * 8;
        #pragma unroll
        for (int ks = 0; ks < 4; ++ks)
            afrag[rt][ks] = *(const bf16x8*)(ap + ks * 512);
        const f32x4 nv4 = *(const f32x4*)(naS + gA * 16 + quad * 4);
        #pragma unroll
        for (int r = 0; r < 4; ++r) na[rt][r] = nv4[r];
    }

    float accw[2][4], accwy[2][4];
    #pragma unroll
    for (int rt = 0; rt < 2; ++rt)
        #pragma unroll
        for (int r = 0; r < 4; ++r) { accw[rt][r] = 0.f; accwy[rt][r] = 0.f; }

    const unsigned short* bbase = Bsw + (size_t)(j0 >> 4) * 2048 + lane * 8;
    const float2* nbb = nbY + j0 + ln16;

    #pragma unroll 4
    for (int ct = 0; ct < 32; ++ct) {
        const unsigned short* bp = bbase + (size_t)ct * 2048;
        bf16x8 bfrag[4];
        #pragma unroll
        for (int ks = 0; ks < 4; ++ks)
            bfrag[ks] = *(const bf16x8*)(bp + ks * 512);
        const float2 nv = nbb[ct * 16];

        #pragma unroll
        for (int rt = 0; rt < 2; ++rt) {
            f32x4 s = {0.f, 0.f, 0.f, 0.f};
            #pragma unroll
            for (int ks = 0; ks < 4; ++ks)
                s = __builtin_amdgcn_mfma_f32_16x16x32_bf16(
                        afrag[rt][ks], bfrag[ks], s, 0, 0, 0);
            #pragma unroll
            for (int r = 0; r < 4; ++r) {
                float d2 = fmaf(NEG2K2_, s[r], na[rt][r] + nv.x);
                d2 = fmaxf(d2, 0.f);
                float w = __builtin_amdgcn_exp2f(-__builtin_amdgcn_sqrtf(d2));
                accw[rt][r] += w;
                accwy[rt][r] = fmaf(w, nv.y, accwy[rt][r]);
            }
        }
    }

    // reduce over the 16 column-lanes, one atomic per row
    #pragma unroll
    for (int rt = 0; rt < 2; ++rt)
        #pragma unroll
        for (int r = 0; r < 4; ++r) {
            float w  = accw[rt][r];
            float wy = accwy[rt][r];
            #pragma unroll
            for (int m = 1; m <= 8; m <<= 1) {
                w  += __shfl_xor(w,  m, 64);
                wy += __shfl_xor(wy, m, 64);
            }
            if (ln16 == 0) {
                int rowi = i0 + wv * 32 + rt * 16 + quad * 4 + r;
                atomicAdd(&sumw[rowi],  w);
                atomicAdd(&sumwy[rowi], wy);
            }
        }
}

// ---------------------------------------------------------------------------
__global__ __launch_bounds__(1024) void finish_kernel(
    const float* __restrict__ Y, const float* __restrict__ sumw,
    const float* __restrict__ sumwy, float* __restrict__ out)
{
    __shared__ float red[16];
    const int tid = threadIdx.x;
    float acc = 0.f;
    #pragma unroll
    for (int i = 0; i < 2; ++i) {
        int idx = tid + i * 1024;
        float4 w4  = ((const float4*)sumw)[idx];
        float4 wy4 = ((const float4*)sumwy)[idx];
        float4 y4  = ((const float4*)Y)[idx];
        const float we[4]  = {w4.x, w4.y, w4.z, w4.w};
        const float wye[4] = {wy4.x, wy4.y, wy4.z, wy4.w};
        const float ye[4]  = {y4.x, y4.y, y4.z, y4.w};
        #pragma unroll
        for (int e = 0; e < 4; ++e) {
            float pred = wye[e] * __builtin_amdgcn_rcpf(we[e]);
            float d = ye[e] - pred;
            acc = fmaf(d, d, acc);
        }
    }
    #pragma unroll
    for (int m = 1; m < 64; m <<= 1) acc += __shfl_xor(acc, m, 64);
    if ((tid & 63) == 0) red[tid >> 6] = acc;
    __syncthreads();
    if (tid < 64) {
        float v = (tid < 16) ? red[tid] : 0.f;
        #pragma unroll
        for (int m = 1; m < 16; m <<= 1) v += __shfl_xor(v, m, 64);
        if (tid == 0) out[0] = v;
    }
}

// ---------------------------------------------------------------------------
extern "C" void kernel_launch(void* const* d_in, const int* in_sizes, int n_in,
                              void* d_out, int out_size, void* d_ws, size_t ws_size,
                              hipStream_t stream)
{
    const float* L    = (const float*)d_in[0];
    const float* X    = (const float*)d_in[1];
    const float* Y    = (const float*)d_in[2];
    const float* Wnet = (const float*)d_in[3];
    const float* bnet = (const float*)d_in[4];
    float* out = (float*)d_out;

    // ws: Abf 2MB | Bbf 2MB | Wbf 32KB | naS 32KB | nbY 64KB | sumw 32KB | sumwy 32KB
    char* ws = (char*)d_ws;
    unsigned short* Abf = (unsigned short*)(ws);
    unsigned short* Bbf = (unsigned short*)(ws + (size_t)2 * 1024 * 1024);
    uint32_t* Wbf  = (uint32_t*)(ws + (size_t)4 * 1024 * 1024);
    float*    naS  = (float*)   (ws + (size_t)4 * 1024 * 1024 + 32 * 1024);
    float2*   nbYp = (float2*)  (ws + (size_t)4 * 1024 * 1024 + 64 * 1024);
    float*    sumw = (float*)   (ws + (size_t)4 * 1024 * 1024 + 128 * 1024);
    float*    sumwy= (float*)   (ws + (size_t)4 * 1024 * 1024 + 160 * 1024);

    wprep_kernel<<<32, 256, 0, stream>>>(Wnet, Y, Wbf, naS, nbYp, sumw, sumwy);
    prep_kernel<<<1024, 256, 0, stream>>>(L, X, Wbf, bnet, Abf, Bbf, naS, nbYp);
    pairwise_kernel<<<dim3(N_ / 128, 16), 256, 0, stream>>>(Abf, Bbf, naS, nbYp,
                                                            sumw, sumwy);
    finish_kernel<<<1, 1024, 0, stream>>>(Y, sumw, sumwy, out);
}